// Round 6
// baseline (348.273 us; speedup 1.0000x reference)
//
#include <hip/hip_runtime.h>

// ESMProjectionHead — f32 in, f32 out. B=64, L=4096, D=128, RL=64, RD=16, DOUT=512
// R13 — DISCRIMINATING PROBE ROUND.
//   History: R11 (occupancy/prefetch/DPP) neutral; R12 (halve work via chunk-skip)
//   -6us where -35 predicted. k1 responds to neither scheduling nor work.
//   Theory A (harness-gated): k1's wall time is pinned by overlap/contention with
//     the harness's 512MB poison-fill + input restores (R8: k1_proj 80us ~= fill
//     77us, VALUBusy 15%, HBM 11% -> starved on vmcnt behind a 6.9TB/s fill).
//   Theory B (intrinsic): k1 really costs ~70us for an unknown structural reason.
//   Probe: launch k1_fused 4x (idempotent: same inputs -> same Part bits).
//   The 3 extra launches run outside the contention window at true standalone cost.
//     delta = dur_us - 255.1 ~= 3 * k1_standalone.
//     Pre-committed read: delta < 120 -> Theory A (k1 < 40; harness floor; revert
//     probes, declare near-roofline). delta > 150 -> Theory B (k1 >= 50; attack
//     k1 structure next). Warm copies >77us would also surface in top-5 counters.
//   Everything else byte-identical to R12 so the 255.1 baseline subtraction holds.

__device__ __forceinline__ float quad_reduce_add(float v) {
    int a = __builtin_amdgcn_mov_dpp(__float_as_int(v), 0xB1, 0xF, 0xF, true); // [1,0,3,2]
    v += __int_as_float(a);
    int b = __builtin_amdgcn_mov_dpp(__float_as_int(v), 0x4E, 0xF, 0xF, true); // [2,3,0,1]
    v += __int_as_float(b);
    return v;
}

// ---------------- mask-layout detection (fallback only) -------------------
__global__ __launch_bounds__(256) void detect_mask(
    const unsigned int* __restrict__ m, int* __restrict__ flag)
{
    unsigned int v = 0;
    int base = (blockIdx.x * 256 + threadIdx.x) * 4;
#pragma unroll
    for (int i = 0; i < 4; ++i) v |= m[base + i];
    unsigned long long any = __ballot(v > 1u);
    if ((threadIdx.x & 63) == 0 && any) atomicOr(flag, 1);
}

// ---------------- Kernel 1 (fused): Y = (X@Bc)*mask in LDS; Part = A^T@Y --
#define BCS_CHUNK 516   // 32 ks * 16 cols + 4 pad: chunk q starts at bank 4q
__global__ __launch_bounds__(256, 4) void k1_fused(
    const float* __restrict__ emb,          // [64,4096,128]
    const void* __restrict__ maskp,         // [64,4096] bool (byte or int32)
    const float* __restrict__ Bc,           // [128,16]
    const float* __restrict__ Ac,           // [4096,64]
    float* __restrict__ Part,               // [16][64][1024]
    const int* __restrict__ flag,           // fallback detection result
    int byte_mode_arg)                      // >=0: known layout; <0: use *flag
{
    __shared__ __align__(16) float BcS[4 * BCS_CHUNK];  // 8.1 KB swizzled
    __shared__ __align__(16) float YsL[256 * 16];       // 16 KB: Ys, then Lred

    const int tid = threadIdx.x;
    const int q   = tid & 3;                // owns ks {16j + 4q + i}
    const int r2  = tid >> 2;               // 0..63: rows {r2 + 64m}
    const int b   = blockIdx.x >> 4;
    const int c   = blockIdx.x & 15;        // 256-row chunk
    const long l0 = (long)c * 256;
    const int byte_mode = (byte_mode_arg >= 0) ? byte_mode_arg : *flag;

    // ---- chunk skip: contiguous mask -> first-row-masked chunk is all zero ----
    {
        long mrow0 = (long)b * 4096 + l0;
        bool chunk_valid = byte_mode
            ? (((const unsigned char*)maskp)[mrow0] != 0)
            : (((const int*)maskp)[mrow0] != 0);
        if (!chunk_valid) {
            float4 z = {0.f, 0.f, 0.f, 0.f};
            *(float4*)(Part + ((long)(c * 64 + b)) * 1024 + tid * 4) = z;
            return;
        }
    }

    // ---- early mask loads ----
    float mv[4];
#pragma unroll
    for (int m = 0; m < 4; ++m) {
        long midx = (long)b * 4096 + l0 + r2 + m * 64;
        bool mb = byte_mode ? (((const unsigned char*)maskp)[midx] != 0)
                            : (((const int*)maskp)[midx] != 0);
        mv[m] = mb ? 1.f : 0.f;
    }

    // stage Bc: chunk qk=(k>>2)&3 holds its 32 ks ordered (j=k>>4, i=k&3)
#pragma unroll
    for (int i = 0; i < 8; ++i) {
        int e = i * 256 + tid;              // [0,2048)
        int k = e >> 4, col = e & 15;
        int qk = (k >> 2) & 3;
        int loc = ((k >> 4) << 2) | (k & 3);
        BcS[qk * BCS_CHUNK + loc * 16 + col] = Bc[e];
    }
    __syncthreads();

    // ---- Y phase: 4 rows/thread, ks {16j+4q+i}, 2-stage emb prefetch ----
    float y[4][16];
#pragma unroll
    for (int m = 0; m < 4; ++m)
#pragma unroll
        for (int j = 0; j < 16; ++j) y[m][j] = 0.f;

    const float* bq = BcS + q * BCS_CHUNK;  // +4-bank offset per q: conflict-free
    const float* xb = emb + ((long)b * 4096 + l0 + r2) * 128 + q * 4;

    float4 cur0 = *(const float4*)(xb + 0L * 64 * 128);
    float4 cur1 = *(const float4*)(xb + 1L * 64 * 128);
    float4 cur2 = *(const float4*)(xb + 2L * 64 * 128);
    float4 cur3 = *(const float4*)(xb + 3L * 64 * 128);

#pragma unroll
    for (int j4 = 0; j4 < 8; ++j4) {
        float4 n0, n1, n2, n3;
        if (j4 < 7) {
            n0 = *(const float4*)(xb + 0L * 64 * 128 + (j4 + 1) * 16);
            n1 = *(const float4*)(xb + 1L * 64 * 128 + (j4 + 1) * 16);
            n2 = *(const float4*)(xb + 2L * 64 * 128 + (j4 + 1) * 16);
            n3 = *(const float4*)(xb + 3L * 64 * 128 + (j4 + 1) * 16);
        }
#pragma unroll
        for (int i = 0; i < 4; ++i) {
            float x0 = (i == 0) ? cur0.x : (i == 1) ? cur0.y : (i == 2) ? cur0.z : cur0.w;
            float x1 = (i == 0) ? cur1.x : (i == 1) ? cur1.y : (i == 2) ? cur1.z : cur1.w;
            float x2 = (i == 0) ? cur2.x : (i == 1) ? cur2.y : (i == 2) ? cur2.z : cur2.w;
            float x3 = (i == 0) ? cur3.x : (i == 1) ? cur3.y : (i == 2) ? cur3.z : cur3.w;
#pragma unroll
            for (int c4 = 0; c4 < 4; ++c4) {
                float4 bv = *(const float4*)(bq + (j4 * 4 + i) * 16 + c4 * 4);
                y[0][c4 * 4 + 0] += x0 * bv.x; y[0][c4 * 4 + 1] += x0 * bv.y;
                y[0][c4 * 4 + 2] += x0 * bv.z; y[0][c4 * 4 + 3] += x0 * bv.w;
                y[1][c4 * 4 + 0] += x1 * bv.x; y[1][c4 * 4 + 1] += x1 * bv.y;
                y[1][c4 * 4 + 2] += x1 * bv.z; y[1][c4 * 4 + 3] += x1 * bv.w;
                y[2][c4 * 4 + 0] += x2 * bv.x; y[2][c4 * 4 + 1] += x2 * bv.y;
                y[2][c4 * 4 + 2] += x2 * bv.z; y[2][c4 * 4 + 3] += x2 * bv.w;
                y[3][c4 * 4 + 0] += x3 * bv.x; y[3][c4 * 4 + 1] += x3 * bv.y;
                y[3][c4 * 4 + 2] += x3 * bv.z; y[3][c4 * 4 + 3] += x3 * bv.w;
            }
        }
        if (j4 < 7) { cur0 = n0; cur1 = n1; cur2 = n2; cur3 = n3; }
    }

    // reduce the 4 K-quarters across each quad — pure VALU (DPP)
#pragma unroll
    for (int m = 0; m < 4; ++m)
#pragma unroll
        for (int j = 0; j < 16; ++j)
            y[m][j] = quad_reduce_add(y[m][j]);

    // mask, select this lane's col-quad, store to LDS Y
#pragma unroll
    for (int m = 0; m < 4; ++m) {
        float4 o;
        if (q == 0)      o = make_float4(y[m][0],  y[m][1],  y[m][2],  y[m][3]);
        else if (q == 1) o = make_float4(y[m][4],  y[m][5],  y[m][6],  y[m][7]);
        else if (q == 2) o = make_float4(y[m][8],  y[m][9],  y[m][10], y[m][11]);
        else             o = make_float4(y[m][12], y[m][13], y[m][14], y[m][15]);
        o.x *= mv[m]; o.y *= mv[m]; o.z *= mv[m]; o.w *= mv[m];
        *(float4*)(YsL + (r2 + m * 64) * 16 + q * 4) = o;
    }
    __syncthreads();

    // ---- U phase: acc[4][4] = A_slice^T @ Y_slice ----
    const int cg = tid & 3;                 // col quad
    const int kg = (tid >> 2) & 15;         // k quad
    const int ls = tid >> 6;                // 64-row slice
    const float* ap = Ac + (l0 + ls * 64) * 64 + kg * 4;    // coalesced, L2-shared
    const float* yl = YsL + (ls * 64) * 16 + cg * 4;        // broadcast-friendly

    float acc[4][4];
#pragma unroll
    for (int i = 0; i < 4; ++i)
#pragma unroll
        for (int j = 0; j < 4; ++j) acc[i][j] = 0.f;

#pragma unroll 8
    for (int l = 0; l < 64; ++l) {
        float4 a4 = *(const float4*)(ap + l * 64);
        float4 y4 = *(const float4*)(yl + l * 16);
        acc[0][0] += a4.x * y4.x; acc[0][1] += a4.x * y4.y;
        acc[0][2] += a4.x * y4.z; acc[0][3] += a4.x * y4.w;
        acc[1][0] += a4.y * y4.x; acc[1][1] += a4.y * y4.y;
        acc[1][2] += a4.y * y4.z; acc[1][3] += a4.y * y4.w;
        acc[2][0] += a4.z * y4.x; acc[2][1] += a4.z * y4.y;
        acc[2][2] += a4.z * y4.z; acc[2][3] += a4.z * y4.w;
        acc[3][0] += a4.w * y4.x; acc[3][1] += a4.w * y4.y;
        acc[3][2] += a4.w * y4.z; acc[3][3] += a4.w * y4.w;
    }
    __syncthreads();                        // Ys dead -> alias as Lred

    float* Lred = YsL;                      // [4][64][16]
#pragma unroll
    for (int i = 0; i < 4; ++i) {
        float4 p = {acc[i][0], acc[i][1], acc[i][2], acc[i][3]};
        *(float4*)(&Lred[ls * 1024 + (kg * 4 + i) * 16 + cg * 4]) = p;
    }
    __syncthreads();

    const int k  = tid >> 2;                // 0..63
    const int cq = tid & 3;
    float4 s0 = *(const float4*)(&Lred[0 * 1024 + k * 16 + cq * 4]);
    float4 s1 = *(const float4*)(&Lred[1 * 1024 + k * 16 + cq * 4]);
    float4 s2 = *(const float4*)(&Lred[2 * 1024 + k * 16 + cq * 4]);
    float4 s3 = *(const float4*)(&Lred[3 * 1024 + k * 16 + cq * 4]);
    float4 s;
    s.x = s0.x + s1.x + s2.x + s3.x;
    s.y = s0.y + s1.y + s2.y + s3.y;
    s.z = s0.z + s1.z + s2.z + s3.z;
    s.w = s0.w + s1.w + s2.w + s3.w;
    *(float4*)(Part + ((long)(c * 64 + b)) * 1024 + k * 16 + cq * 4) = s;
}

// ---------------- Kernel 2a: U-reduce + z = U @ Hc (col-quartered) --------
__global__ __launch_bounds__(256) void k2a(
    const float* __restrict__ Part,         // [16][64][1024]
    const float* __restrict__ Hc,           // [1024,512]
    float* __restrict__ zbuf)               // [64,512]
{
    __shared__ __align__(16) float Us[1024];     // 4 KB
    __shared__ __align__(16) float hp[8][128];   // 4 KB partials

    const int tid = threadIdx.x;            // 256 threads
    const int b   = blockIdx.x >> 2;
    const int jq  = blockIdx.x & 3;

    {
        const float* pb = Part + (long)b * 1024 + tid * 4;
        float4 s = {0.f, 0.f, 0.f, 0.f};
#pragma unroll
        for (int cc = 0; cc < 16; ++cc) {
            float4 v = *(const float4*)(pb + (long)cc * 64 * 1024);
            s.x += v.x; s.y += v.y; s.z += v.z; s.w += v.w;
        }
        *(float4*)(Us + tid * 4) = s;
    }
    __syncthreads();

    const int c4 = (tid & 31) * 4;          // col within 128-slice
    const int kq = tid >> 5;                // 0..7
    const int k0 = kq * 128;
    float a0 = 0.f, a1 = 0.f, a2 = 0.f, a3 = 0.f;
    for (int k4 = 0; k4 < 128; k4 += 4) {
        float4 u = *(const float4*)(Us + k0 + k4);
        const float* hcp = Hc + (long)(k0 + k4) * 512 + jq * 128 + c4;
        float4 w0  = *(const float4*)(hcp);
        float4 w1v = *(const float4*)(hcp + 512);
        float4 w2v = *(const float4*)(hcp + 1024);
        float4 w3  = *(const float4*)(hcp + 1536);
        a0 += u.x * w0.x + u.y * w1v.x + u.z * w2v.x + u.w * w3.x;
        a1 += u.x * w0.y + u.y * w1v.y + u.z * w2v.y + u.w * w3.y;
        a2 += u.x * w0.z + u.y * w1v.z + u.z * w2v.z + u.w * w3.z;
        a3 += u.x * w0.w + u.y * w1v.w + u.z * w2v.w + u.w * w3.w;
    }
    float4 p = {a0, a1, a2, a3};
    *(float4*)(&hp[kq][c4]) = p;
    __syncthreads();

    if (tid < 128) {
        float z = hp[0][tid] + hp[1][tid] + hp[2][tid] + hp[3][tid]
                + hp[4][tid] + hp[5][tid] + hp[6][tid] + hp[7][tid];
        zbuf[(long)b * 512 + jq * 128 + tid] = z;
    }
}

// ---------------- Kernel 2b: h = z @ W1 + b1 (raw) + partial LN stats -----
__global__ __launch_bounds__(256) void k2b(
    const float* __restrict__ zbuf,         // [64,512]
    const float* __restrict__ W1,           // [512,512]
    const float* __restrict__ b1,
    float* __restrict__ gbuf,               // [64,512] raw h
    float* __restrict__ pstat)              // [64][4][2] partial {sum, sumsq}
{
    __shared__ __align__(16) float zs[512];      // 2 KB
    __shared__ __align__(16) float hp[8][128];   // 4 KB
    __shared__ float red[8];

    const int tid = threadIdx.x;
    const int b   = blockIdx.x >> 2;
    const int jq  = blockIdx.x & 3;

    if (tid < 128)
        *(float4*)(zs + tid * 4) = *(const float4*)(zbuf + (long)b * 512 + tid * 4);
    __syncthreads();

    const int c4 = (tid & 31) * 4;
    const int kq = tid >> 5;
    const int k0 = kq * 64;                 // K=512 split 8-way
    float a0 = 0.f, a1 = 0.f, a2 = 0.f, a3 = 0.f;
    for (int k4 = 0; k4 < 64; k4 += 4) {
        float4 u = *(const float4*)(zs + k0 + k4);
        const float* wp = W1 + (long)(k0 + k4) * 512 + jq * 128 + c4;
        float4 w0  = *(const float4*)(wp);
        float4 w1v = *(const float4*)(wp + 512);
        float4 w2v = *(const float4*)(wp + 1024);
        float4 w3  = *(const float4*)(wp + 1536);
        a0 += u.x * w0.x + u.y * w1v.x + u.z * w2v.x + u.w * w3.x;
        a1 += u.x * w0.y + u.y * w1v.y + u.z * w2v.y + u.w * w3.y;
        a2 += u.x * w0.z + u.y * w1v.z + u.z * w2v.z + u.w * w3.z;
        a3 += u.x * w0.w + u.y * w1v.w + u.z * w2v.w + u.w * w3.w;
    }
    float4 p = {a0, a1, a2, a3};
    *(float4*)(&hp[kq][c4]) = p;
    __syncthreads();

    float s = 0.f, s2 = 0.f;
    if (tid < 128) {
        float hv = hp[0][tid] + hp[1][tid] + hp[2][tid] + hp[3][tid]
                 + hp[4][tid] + hp[5][tid] + hp[6][tid] + hp[7][tid]
                 + b1[jq * 128 + tid];
        gbuf[(long)b * 512 + jq * 128 + tid] = hv;
        s = hv; s2 = hv * hv;
    }
#pragma unroll
    for (int m = 32; m >= 1; m >>= 1) {
        s  += __shfl_xor(s, m);
        s2 += __shfl_xor(s2, m);
    }
    const int wave = tid >> 6, lane = tid & 63;
    if (lane == 0) { red[wave] = s; red[wave + 4] = s2; }
    __syncthreads();
    if (tid == 0) {
        pstat[((long)b * 4 + jq) * 2 + 0] = red[0] + red[1] + red[2] + red[3];
        pstat[((long)b * 4 + jq) * 2 + 1] = red[4] + red[5] + red[6] + red[7];
    }
}

// ---------------- Kernel 2c: LN + ReLU, out = h @ W2 + b2 ------------------
__global__ __launch_bounds__(256) void k2c(
    const float* __restrict__ gbuf,         // [64,512] raw h
    const float* __restrict__ pstat,        // [64][4][2]
    const float* __restrict__ lnw,
    const float* __restrict__ lnb,
    const float* __restrict__ W2,           // [512,512]
    const float* __restrict__ b2,
    float* __restrict__ out)                // [64,512]
{
    __shared__ __align__(16) float hs[512];      // 2 KB (post LN+ReLU)
    __shared__ __align__(16) float hp[8][128];   // 4 KB

    const int tid = threadIdx.x;
    const int b   = blockIdx.x >> 2;
    const int jq  = blockIdx.x & 3;

    float S = 0.f, S2 = 0.f;
#pragma unroll
    for (int qq = 0; qq < 4; ++qq) {
        S  += pstat[((long)b * 4 + qq) * 2 + 0];
        S2 += pstat[((long)b * 4 + qq) * 2 + 1];
    }
    const float mu   = S * (1.f / 512.f);
    const float var  = S2 * (1.f / 512.f) - mu * mu;
    const float rstd = rsqrtf(var + 1e-5f);

    if (tid < 128) {
        float4 g  = *(const float4*)(gbuf + (long)b * 512 + tid * 4);
        float4 w  = *(const float4*)(lnw + tid * 4);
        float4 bb = *(const float4*)(lnb + tid * 4);
        float h0 = (g.x - mu) * rstd * w.x + bb.x;
        float h1 = (g.y - mu) * rstd * w.y + bb.y;
        float h2 = (g.z - mu) * rstd * w.z + bb.z;
        float h3 = (g.w - mu) * rstd * w.w + bb.w;
        h0 = h0 > 0.f ? h0 : 0.f;
        h1 = h1 > 0.f ? h1 : 0.f;
        h2 = h2 > 0.f ? h2 : 0.f;
        h3 = h3 > 0.f ? h3 : 0.f;
        *(float4*)(hs + tid * 4) = make_float4(h0, h1, h2, h3);
    }
    __syncthreads();

    const int c4 = (tid & 31) * 4;
    const int kq = tid >> 5;
    const int k0 = kq * 64;                 // K=512 split 8-way
    float a0 = 0.f, a1 = 0.f, a2 = 0.f, a3 = 0.f;
    for (int k4 = 0; k4 < 64; k4 += 4) {
        float4 u = *(const float4*)(hs + k0 + k4);
        const float* wp = W2 + (long)(k0 + k4) * 512 + jq * 128 + c4;
        float4 w0  = *(const float4*)(wp);
        float4 w1v = *(const float4*)(wp + 512);
        float4 w2v = *(const float4*)(wp + 1024);
        float4 w3  = *(const float4*)(wp + 1536);
        a0 += u.x * w0.x + u.y * w1v.x + u.z * w2v.x + u.w * w3.x;
        a1 += u.x * w0.y + u.y * w1v.y + u.z * w2v.y + u.w * w3.y;
        a2 += u.x * w0.z + u.y * w1v.z + u.z * w2v.z + u.w * w3.z;
        a3 += u.x * w0.w + u.y * w1v.w + u.z * w2v.w + u.w * w3.w;
    }
    float4 p = {a0, a1, a2, a3};
    *(float4*)(&hp[kq][c4]) = p;
    __syncthreads();

    if (tid < 128) {
        float o = hp[0][tid] + hp[1][tid] + hp[2][tid] + hp[3][tid]
                + hp[4][tid] + hp[5][tid] + hp[6][tid] + hp[7][tid]
                + b2[jq * 128 + tid];
        out[(long)b * 512 + jq * 128 + tid] = o;
    }
}

extern "C" void kernel_launch(void* const* d_in, const int* in_sizes, int n_in,
                              void* d_out, int out_size, void* d_ws, size_t ws_size,
                              hipStream_t stream) {
    const float* emb = (const float*)d_in[0];
    const void*  msk = (const void*)d_in[1];
    const float* Bc  = (const float*)d_in[2];
    const float* Ac  = (const float*)d_in[3];
    const float* Hc  = (const float*)d_in[4];
    const float* W1  = (const float*)d_in[5];
    const float* b1  = (const float*)d_in[6];
    const float* lnw = (const float*)d_in[7];
    const float* lnb = (const float*)d_in[8];
    const float* W2  = (const float*)d_in[9];
    const float* b2  = (const float*)d_in[10];

    float* Part  = (float*)d_ws;                              // 4 MB: [16][64][1024]
    int*   flg   = (int*)((char*)d_ws + 4 * 1024 * 1024);     // 4 B (4KB slot)
    float* zbuf  = (float*)((char*)flg + 4096);               // 128 KB
    float* gbuf  = zbuf + 64 * 512;                           // 128 KB
    float* pstat = gbuf + 64 * 512;                           // 2 KB

    // mask layout from in_sizes (bytes), guarded by emb's known byte size.
    int byte_mode = -1;
    if (in_sizes && in_sizes[0] == 64 * 4096 * 128 * 4) {
        if (in_sizes[1] == 64 * 4096)          byte_mode = 1;   // bool bytes
        else if (in_sizes[1] == 64 * 4096 * 4) byte_mode = 0;   // int32
    }
    if (byte_mode < 0) {                     // fallback: runtime detection
        hipMemsetAsync(flg, 0, 4, stream);
        detect_mask<<<64, 256, 0, stream>>>((const unsigned int*)msk, flg);
    }

    // PROBE: 4 idempotent launches of k1_fused. Launch 1 = the real one (inside
    // any harness contention window). Launches 2-4 measure standalone k1 cost:
    // (dur_us - 255.1) / 3 ~= k1_standalone. Same inputs -> same Part bits, so
    // correctness is unaffected.
    for (int rep = 0; rep < 4; ++rep)
        k1_fused<<<1024, 256, 0, stream>>>(emb, msk, Bc, Ac, Part, flg, byte_mode);

    k2a<<<256, 256, 0, stream>>>(Part, Hc, zbuf);
    k2b<<<256, 256, 0, stream>>>(zbuf, W1, b1, gbuf, pstat);
    k2c<<<256, 256, 0, stream>>>(gbuf, pstat, lnw, lnb, W2, b2, (float*)d_out);
}

// Round 7
// 254.164 us; speedup vs baseline: 1.3703x; 1.3703x over previous
//
#include <hip/hip_runtime.h>

// ESMProjectionHead — f32 in, f32 out. B=64, L=4096, D=128, RL=64, RD=16, DOUT=512
// R14: probe revert. R13's 4x-launch probe measured k1_fused standalone = 31us
//      ((348.3-255.1)/3), confirming Theory A: in-window k1 wall time (~70-80us)
//      is contention with the harness's concurrent 512MB poison-fill + restores
//      (R8: k1 at 904 GB/s, VALUBusy 15% = BW-starved). k1 standalone is within
//      1.5x of its 21us emb-read HBM floor; k2 chain ~12us vs ~6us weight floor.
//      This explains R11 (scheduling no-ops) and R12 (work-halving -6us only).
//      This round: exact R12 structure (single k1 launch) = best measured 255.1.

__device__ __forceinline__ float quad_reduce_add(float v) {
    int a = __builtin_amdgcn_mov_dpp(__float_as_int(v), 0xB1, 0xF, 0xF, true); // [1,0,3,2]
    v += __int_as_float(a);
    int b = __builtin_amdgcn_mov_dpp(__float_as_int(v), 0x4E, 0xF, 0xF, true); // [2,3,0,1]
    v += __int_as_float(b);
    return v;
}

// ---------------- mask-layout detection (fallback only) -------------------
__global__ __launch_bounds__(256) void detect_mask(
    const unsigned int* __restrict__ m, int* __restrict__ flag)
{
    unsigned int v = 0;
    int base = (blockIdx.x * 256 + threadIdx.x) * 4;
#pragma unroll
    for (int i = 0; i < 4; ++i) v |= m[base + i];
    unsigned long long any = __ballot(v > 1u);
    if ((threadIdx.x & 63) == 0 && any) atomicOr(flag, 1);
}

// ---------------- Kernel 1 (fused): Y = (X@Bc)*mask in LDS; Part = A^T@Y --
#define BCS_CHUNK 516   // 32 ks * 16 cols + 4 pad: chunk q starts at bank 4q
__global__ __launch_bounds__(256, 4) void k1_fused(
    const float* __restrict__ emb,          // [64,4096,128]
    const void* __restrict__ maskp,         // [64,4096] bool (byte or int32)
    const float* __restrict__ Bc,           // [128,16]
    const float* __restrict__ Ac,           // [4096,64]
    float* __restrict__ Part,               // [16][64][1024]
    const int* __restrict__ flag,           // fallback detection result
    int byte_mode_arg)                      // >=0: known layout; <0: use *flag
{
    __shared__ __align__(16) float BcS[4 * BCS_CHUNK];  // 8.1 KB swizzled
    __shared__ __align__(16) float YsL[256 * 16];       // 16 KB: Ys, then Lred

    const int tid = threadIdx.x;
    const int q   = tid & 3;                // owns ks {16j + 4q + i}
    const int r2  = tid >> 2;               // 0..63: rows {r2 + 64m}
    const int b   = blockIdx.x >> 4;
    const int c   = blockIdx.x & 15;        // 256-row chunk
    const long l0 = (long)c * 256;
    const int byte_mode = (byte_mode_arg >= 0) ? byte_mode_arg : *flag;

    // ---- chunk skip: contiguous mask -> first-row-masked chunk is all zero ----
    {
        long mrow0 = (long)b * 4096 + l0;
        bool chunk_valid = byte_mode
            ? (((const unsigned char*)maskp)[mrow0] != 0)
            : (((const int*)maskp)[mrow0] != 0);
        if (!chunk_valid) {
            float4 z = {0.f, 0.f, 0.f, 0.f};
            *(float4*)(Part + ((long)(c * 64 + b)) * 1024 + tid * 4) = z;
            return;
        }
    }

    // ---- early mask loads ----
    float mv[4];
#pragma unroll
    for (int m = 0; m < 4; ++m) {
        long midx = (long)b * 4096 + l0 + r2 + m * 64;
        bool mb = byte_mode ? (((const unsigned char*)maskp)[midx] != 0)
                            : (((const int*)maskp)[midx] != 0);
        mv[m] = mb ? 1.f : 0.f;
    }

    // stage Bc: chunk qk=(k>>2)&3 holds its 32 ks ordered (j=k>>4, i=k&3)
#pragma unroll
    for (int i = 0; i < 8; ++i) {
        int e = i * 256 + tid;              // [0,2048)
        int k = e >> 4, col = e & 15;
        int qk = (k >> 2) & 3;
        int loc = ((k >> 4) << 2) | (k & 3);
        BcS[qk * BCS_CHUNK + loc * 16 + col] = Bc[e];
    }
    __syncthreads();

    // ---- Y phase: 4 rows/thread, ks {16j+4q+i}, 2-stage emb prefetch ----
    float y[4][16];
#pragma unroll
    for (int m = 0; m < 4; ++m)
#pragma unroll
        for (int j = 0; j < 16; ++j) y[m][j] = 0.f;

    const float* bq = BcS + q * BCS_CHUNK;  // +4-bank offset per q: conflict-free
    const float* xb = emb + ((long)b * 4096 + l0 + r2) * 128 + q * 4;

    float4 cur0 = *(const float4*)(xb + 0L * 64 * 128);
    float4 cur1 = *(const float4*)(xb + 1L * 64 * 128);
    float4 cur2 = *(const float4*)(xb + 2L * 64 * 128);
    float4 cur3 = *(const float4*)(xb + 3L * 64 * 128);

#pragma unroll
    for (int j4 = 0; j4 < 8; ++j4) {
        float4 n0, n1, n2, n3;
        if (j4 < 7) {
            n0 = *(const float4*)(xb + 0L * 64 * 128 + (j4 + 1) * 16);
            n1 = *(const float4*)(xb + 1L * 64 * 128 + (j4 + 1) * 16);
            n2 = *(const float4*)(xb + 2L * 64 * 128 + (j4 + 1) * 16);
            n3 = *(const float4*)(xb + 3L * 64 * 128 + (j4 + 1) * 16);
        }
#pragma unroll
        for (int i = 0; i < 4; ++i) {
            float x0 = (i == 0) ? cur0.x : (i == 1) ? cur0.y : (i == 2) ? cur0.z : cur0.w;
            float x1 = (i == 0) ? cur1.x : (i == 1) ? cur1.y : (i == 2) ? cur1.z : cur1.w;
            float x2 = (i == 0) ? cur2.x : (i == 1) ? cur2.y : (i == 2) ? cur2.z : cur2.w;
            float x3 = (i == 0) ? cur3.x : (i == 1) ? cur3.y : (i == 2) ? cur3.z : cur3.w;
#pragma unroll
            for (int c4 = 0; c4 < 4; ++c4) {
                float4 bv = *(const float4*)(bq + (j4 * 4 + i) * 16 + c4 * 4);
                y[0][c4 * 4 + 0] += x0 * bv.x; y[0][c4 * 4 + 1] += x0 * bv.y;
                y[0][c4 * 4 + 2] += x0 * bv.z; y[0][c4 * 4 + 3] += x0 * bv.w;
                y[1][c4 * 4 + 0] += x1 * bv.x; y[1][c4 * 4 + 1] += x1 * bv.y;
                y[1][c4 * 4 + 2] += x1 * bv.z; y[1][c4 * 4 + 3] += x1 * bv.w;
                y[2][c4 * 4 + 0] += x2 * bv.x; y[2][c4 * 4 + 1] += x2 * bv.y;
                y[2][c4 * 4 + 2] += x2 * bv.z; y[2][c4 * 4 + 3] += x2 * bv.w;
                y[3][c4 * 4 + 0] += x3 * bv.x; y[3][c4 * 4 + 1] += x3 * bv.y;
                y[3][c4 * 4 + 2] += x3 * bv.z; y[3][c4 * 4 + 3] += x3 * bv.w;
            }
        }
        if (j4 < 7) { cur0 = n0; cur1 = n1; cur2 = n2; cur3 = n3; }
    }

    // reduce the 4 K-quarters across each quad — pure VALU (DPP)
#pragma unroll
    for (int m = 0; m < 4; ++m)
#pragma unroll
        for (int j = 0; j < 16; ++j)
            y[m][j] = quad_reduce_add(y[m][j]);

    // mask, select this lane's col-quad, store to LDS Y
#pragma unroll
    for (int m = 0; m < 4; ++m) {
        float4 o;
        if (q == 0)      o = make_float4(y[m][0],  y[m][1],  y[m][2],  y[m][3]);
        else if (q == 1) o = make_float4(y[m][4],  y[m][5],  y[m][6],  y[m][7]);
        else if (q == 2) o = make_float4(y[m][8],  y[m][9],  y[m][10], y[m][11]);
        else             o = make_float4(y[m][12], y[m][13], y[m][14], y[m][15]);
        o.x *= mv[m]; o.y *= mv[m]; o.z *= mv[m]; o.w *= mv[m];
        *(float4*)(YsL + (r2 + m * 64) * 16 + q * 4) = o;
    }
    __syncthreads();

    // ---- U phase: acc[4][4] = A_slice^T @ Y_slice ----
    const int cg = tid & 3;                 // col quad
    const int kg = (tid >> 2) & 15;         // k quad
    const int ls = tid >> 6;                // 64-row slice
    const float* ap = Ac + (l0 + ls * 64) * 64 + kg * 4;    // coalesced, L2-shared
    const float* yl = YsL + (ls * 64) * 16 + cg * 4;        // broadcast-friendly

    float acc[4][4];
#pragma unroll
    for (int i = 0; i < 4; ++i)
#pragma unroll
        for (int j = 0; j < 4; ++j) acc[i][j] = 0.f;

#pragma unroll 8
    for (int l = 0; l < 64; ++l) {
        float4 a4 = *(const float4*)(ap + l * 64);
        float4 y4 = *(const float4*)(yl + l * 16);
        acc[0][0] += a4.x * y4.x; acc[0][1] += a4.x * y4.y;
        acc[0][2] += a4.x * y4.z; acc[0][3] += a4.x * y4.w;
        acc[1][0] += a4.y * y4.x; acc[1][1] += a4.y * y4.y;
        acc[1][2] += a4.y * y4.z; acc[1][3] += a4.y * y4.w;
        acc[2][0] += a4.z * y4.x; acc[2][1] += a4.z * y4.y;
        acc[2][2] += a4.z * y4.z; acc[2][3] += a4.z * y4.w;
        acc[3][0] += a4.w * y4.x; acc[3][1] += a4.w * y4.y;
        acc[3][2] += a4.w * y4.z; acc[3][3] += a4.w * y4.w;
    }
    __syncthreads();                        // Ys dead -> alias as Lred

    float* Lred = YsL;                      // [4][64][16]
#pragma unroll
    for (int i = 0; i < 4; ++i) {
        float4 p = {acc[i][0], acc[i][1], acc[i][2], acc[i][3]};
        *(float4*)(&Lred[ls * 1024 + (kg * 4 + i) * 16 + cg * 4]) = p;
    }
    __syncthreads();

    const int k  = tid >> 2;                // 0..63
    const int cq = tid & 3;
    float4 s0 = *(const float4*)(&Lred[0 * 1024 + k * 16 + cq * 4]);
    float4 s1 = *(const float4*)(&Lred[1 * 1024 + k * 16 + cq * 4]);
    float4 s2 = *(const float4*)(&Lred[2 * 1024 + k * 16 + cq * 4]);
    float4 s3 = *(const float4*)(&Lred[3 * 1024 + k * 16 + cq * 4]);
    float4 s;
    s.x = s0.x + s1.x + s2.x + s3.x;
    s.y = s0.y + s1.y + s2.y + s3.y;
    s.z = s0.z + s1.z + s2.z + s3.z;
    s.w = s0.w + s1.w + s2.w + s3.w;
    *(float4*)(Part + ((long)(c * 64 + b)) * 1024 + k * 16 + cq * 4) = s;
}

// ---------------- Kernel 2a: U-reduce + z = U @ Hc (col-quartered) --------
__global__ __launch_bounds__(256) void k2a(
    const float* __restrict__ Part,         // [16][64][1024]
    const float* __restrict__ Hc,           // [1024,512]
    float* __restrict__ zbuf)               // [64,512]
{
    __shared__ __align__(16) float Us[1024];     // 4 KB
    __shared__ __align__(16) float hp[8][128];   // 4 KB partials

    const int tid = threadIdx.x;            // 256 threads
    const int b   = blockIdx.x >> 2;
    const int jq  = blockIdx.x & 3;

    {
        const float* pb = Part + (long)b * 1024 + tid * 4;
        float4 s = {0.f, 0.f, 0.f, 0.f};
#pragma unroll
        for (int cc = 0; cc < 16; ++cc) {
            float4 v = *(const float4*)(pb + (long)cc * 64 * 1024);
            s.x += v.x; s.y += v.y; s.z += v.z; s.w += v.w;
        }
        *(float4*)(Us + tid * 4) = s;
    }
    __syncthreads();

    const int c4 = (tid & 31) * 4;          // col within 128-slice
    const int kq = tid >> 5;                // 0..7
    const int k0 = kq * 128;
    float a0 = 0.f, a1 = 0.f, a2 = 0.f, a3 = 0.f;
    for (int k4 = 0; k4 < 128; k4 += 4) {
        float4 u = *(const float4*)(Us + k0 + k4);
        const float* hcp = Hc + (long)(k0 + k4) * 512 + jq * 128 + c4;
        float4 w0  = *(const float4*)(hcp);
        float4 w1v = *(const float4*)(hcp + 512);
        float4 w2v = *(const float4*)(hcp + 1024);
        float4 w3  = *(const float4*)(hcp + 1536);
        a0 += u.x * w0.x + u.y * w1v.x + u.z * w2v.x + u.w * w3.x;
        a1 += u.x * w0.y + u.y * w1v.y + u.z * w2v.y + u.w * w3.y;
        a2 += u.x * w0.z + u.y * w1v.z + u.z * w2v.z + u.w * w3.z;
        a3 += u.x * w0.w + u.y * w1v.w + u.z * w2v.w + u.w * w3.w;
    }
    float4 p = {a0, a1, a2, a3};
    *(float4*)(&hp[kq][c4]) = p;
    __syncthreads();

    if (tid < 128) {
        float z = hp[0][tid] + hp[1][tid] + hp[2][tid] + hp[3][tid]
                + hp[4][tid] + hp[5][tid] + hp[6][tid] + hp[7][tid];
        zbuf[(long)b * 512 + jq * 128 + tid] = z;
    }
}

// ---------------- Kernel 2b: h = z @ W1 + b1 (raw) + partial LN stats -----
__global__ __launch_bounds__(256) void k2b(
    const float* __restrict__ zbuf,         // [64,512]
    const float* __restrict__ W1,           // [512,512]
    const float* __restrict__ b1,
    float* __restrict__ gbuf,               // [64,512] raw h
    float* __restrict__ pstat)              // [64][4][2] partial {sum, sumsq}
{
    __shared__ __align__(16) float zs[512];      // 2 KB
    __shared__ __align__(16) float hp[8][128];   // 4 KB
    __shared__ float red[8];

    const int tid = threadIdx.x;
    const int b   = blockIdx.x >> 2;
    const int jq  = blockIdx.x & 3;

    if (tid < 128)
        *(float4*)(zs + tid * 4) = *(const float4*)(zbuf + (long)b * 512 + tid * 4);
    __syncthreads();

    const int c4 = (tid & 31) * 4;
    const int kq = tid >> 5;
    const int k0 = kq * 64;                 // K=512 split 8-way
    float a0 = 0.f, a1 = 0.f, a2 = 0.f, a3 = 0.f;
    for (int k4 = 0; k4 < 64; k4 += 4) {
        float4 u = *(const float4*)(zs + k0 + k4);
        const float* wp = W1 + (long)(k0 + k4) * 512 + jq * 128 + c4;
        float4 w0  = *(const float4*)(wp);
        float4 w1v = *(const float4*)(wp + 512);
        float4 w2v = *(const float4*)(wp + 1024);
        float4 w3  = *(const float4*)(wp + 1536);
        a0 += u.x * w0.x + u.y * w1v.x + u.z * w2v.x + u.w * w3.x;
        a1 += u.x * w0.y + u.y * w1v.y + u.z * w2v.y + u.w * w3.y;
        a2 += u.x * w0.z + u.y * w1v.z + u.z * w2v.z + u.w * w3.z;
        a3 += u.x * w0.w + u.y * w1v.w + u.z * w2v.w + u.w * w3.w;
    }
    float4 p = {a0, a1, a2, a3};
    *(float4*)(&hp[kq][c4]) = p;
    __syncthreads();

    float s = 0.f, s2 = 0.f;
    if (tid < 128) {
        float hv = hp[0][tid] + hp[1][tid] + hp[2][tid] + hp[3][tid]
                 + hp[4][tid] + hp[5][tid] + hp[6][tid] + hp[7][tid]
                 + b1[jq * 128 + tid];
        gbuf[(long)b * 512 + jq * 128 + tid] = hv;
        s = hv; s2 = hv * hv;
    }
#pragma unroll
    for (int m = 32; m >= 1; m >>= 1) {
        s  += __shfl_xor(s, m);
        s2 += __shfl_xor(s2, m);
    }
    const int wave = tid >> 6, lane = tid & 63;
    if (lane == 0) { red[wave] = s; red[wave + 4] = s2; }
    __syncthreads();
    if (tid == 0) {
        pstat[((long)b * 4 + jq) * 2 + 0] = red[0] + red[1] + red[2] + red[3];
        pstat[((long)b * 4 + jq) * 2 + 1] = red[4] + red[5] + red[6] + red[7];
    }
}

// ---------------- Kernel 2c: LN + ReLU, out = h @ W2 + b2 ------------------
__global__ __launch_bounds__(256) void k2c(
    const float* __restrict__ gbuf,         // [64,512] raw h
    const float* __restrict__ pstat,        // [64][4][2]
    const float* __restrict__ lnw,
    const float* __restrict__ lnb,
    const float* __restrict__ W2,           // [512,512]
    const float* __restrict__ b2,
    float* __restrict__ out)                // [64,512]
{
    __shared__ __align__(16) float hs[512];      // 2 KB (post LN+ReLU)
    __shared__ __align__(16) float hp[8][128];   // 4 KB

    const int tid = threadIdx.x;
    const int b   = blockIdx.x >> 2;
    const int jq  = blockIdx.x & 3;

    float S = 0.f, S2 = 0.f;
#pragma unroll
    for (int qq = 0; qq < 4; ++qq) {
        S  += pstat[((long)b * 4 + qq) * 2 + 0];
        S2 += pstat[((long)b * 4 + qq) * 2 + 1];
    }
    const float mu   = S * (1.f / 512.f);
    const float var  = S2 * (1.f / 512.f) - mu * mu;
    const float rstd = rsqrtf(var + 1e-5f);

    if (tid < 128) {
        float4 g  = *(const float4*)(gbuf + (long)b * 512 + tid * 4);
        float4 w  = *(const float4*)(lnw + tid * 4);
        float4 bb = *(const float4*)(lnb + tid * 4);
        float h0 = (g.x - mu) * rstd * w.x + bb.x;
        float h1 = (g.y - mu) * rstd * w.y + bb.y;
        float h2 = (g.z - mu) * rstd * w.z + bb.z;
        float h3 = (g.w - mu) * rstd * w.w + bb.w;
        h0 = h0 > 0.f ? h0 : 0.f;
        h1 = h1 > 0.f ? h1 : 0.f;
        h2 = h2 > 0.f ? h2 : 0.f;
        h3 = h3 > 0.f ? h3 : 0.f;
        *(float4*)(hs + tid * 4) = make_float4(h0, h1, h2, h3);
    }
    __syncthreads();

    const int c4 = (tid & 31) * 4;
    const int kq = tid >> 5;
    const int k0 = kq * 64;                 // K=512 split 8-way
    float a0 = 0.f, a1 = 0.f, a2 = 0.f, a3 = 0.f;
    for (int k4 = 0; k4 < 64; k4 += 4) {
        float4 u = *(const float4*)(hs + k0 + k4);
        const float* wp = W2 + (long)(k0 + k4) * 512 + jq * 128 + c4;
        float4 w0  = *(const float4*)(wp);
        float4 w1v = *(const float4*)(wp + 512);
        float4 w2v = *(const float4*)(wp + 1024);
        float4 w3  = *(const float4*)(wp + 1536);
        a0 += u.x * w0.x + u.y * w1v.x + u.z * w2v.x + u.w * w3.x;
        a1 += u.x * w0.y + u.y * w1v.y + u.z * w2v.y + u.w * w3.y;
        a2 += u.x * w0.z + u.y * w1v.z + u.z * w2v.z + u.w * w3.z;
        a3 += u.x * w0.w + u.y * w1v.w + u.z * w2v.w + u.w * w3.w;
    }
    float4 p = {a0, a1, a2, a3};
    *(float4*)(&hp[kq][c4]) = p;
    __syncthreads();

    if (tid < 128) {
        float o = hp[0][tid] + hp[1][tid] + hp[2][tid] + hp[3][tid]
                + hp[4][tid] + hp[5][tid] + hp[6][tid] + hp[7][tid]
                + b2[jq * 128 + tid];
        out[(long)b * 512 + jq * 128 + tid] = o;
    }
}

extern "C" void kernel_launch(void* const* d_in, const int* in_sizes, int n_in,
                              void* d_out, int out_size, void* d_ws, size_t ws_size,
                              hipStream_t stream) {
    const float* emb = (const float*)d_in[0];
    const void*  msk = (const void*)d_in[1];
    const float* Bc  = (const float*)d_in[2];
    const float* Ac  = (const float*)d_in[3];
    const float* Hc  = (const float*)d_in[4];
    const float* W1  = (const float*)d_in[5];
    const float* b1  = (const float*)d_in[6];
    const float* lnw = (const float*)d_in[7];
    const float* lnb = (const float*)d_in[8];
    const float* W2  = (const float*)d_in[9];
    const float* b2  = (const float*)d_in[10];

    float* Part  = (float*)d_ws;                              // 4 MB: [16][64][1024]
    int*   flg   = (int*)((char*)d_ws + 4 * 1024 * 1024);     // 4 B (4KB slot)
    float* zbuf  = (float*)((char*)flg + 4096);               // 128 KB
    float* gbuf  = zbuf + 64 * 512;                           // 128 KB
    float* pstat = gbuf + 64 * 512;                           // 2 KB

    // mask layout from in_sizes (bytes), guarded by emb's known byte size.
    int byte_mode = -1;
    if (in_sizes && in_sizes[0] == 64 * 4096 * 128 * 4) {
        if (in_sizes[1] == 64 * 4096)          byte_mode = 1;   // bool bytes
        else if (in_sizes[1] == 64 * 4096 * 4) byte_mode = 0;   // int32
    }
    if (byte_mode < 0) {                     // fallback: runtime detection
        hipMemsetAsync(flg, 0, 4, stream);
        detect_mask<<<64, 256, 0, stream>>>((const unsigned int*)msk, flg);
    }

    k1_fused<<<1024, 256, 0, stream>>>(emb, msk, Bc, Ac, Part, flg, byte_mode);
    k2a<<<256, 256, 0, stream>>>(Part, Hc, zbuf);
    k2b<<<256, 256, 0, stream>>>(zbuf, W1, b1, gbuf, pstat);
    k2c<<<256, 256, 0, stream>>>(gbuf, pstat, lnw, lnb, W2, b2, (float*)d_out);
}